// Round 1
// baseline (834.638 us; speedup 1.0000x reference)
//
#include <hip/hip_runtime.h>

#define NEGV -1e30f
static constexpr int BATCH = 64;
static constexpr int NN = 512;
static constexpr int MM = 512;
static constexpr int NM = NN * MM;
static constexpr size_t TOTAL = (size_t)BATCH * NM;

// ---------------------------------------------------------------------------
// K1: anti-diagonal wavefront DP. One block per (batch, direction).
// Thread i owns row i. 3 rotating LDS diagonal buffers; slots k, k-1, k-2 are
// distinct mod 3, so ONE barrier per diagonal is sufficient.
// dir=1 runs the same DP on the index-reversed problem (backward pass).
// ---------------------------------------------------------------------------
__global__ __launch_bounds__(512) void dp_kernel(const float* __restrict__ D,
                                                 float* __restrict__ Rf,
                                                 float* __restrict__ Rb) {
    __shared__ float buf[3][NN];
    const int blk = blockIdx.x;
    const int b = blk & (BATCH - 1);
    const int dir = blk >> 6;
    const float* Db = D + (size_t)b * NM;
    float* R = (dir ? Rb : Rf) + (size_t)b * NM;
    const int i = threadIdx.x;

    // preload this thread's first row element (j = 0)
    int idx0 = i * MM;
    if (dir) idx0 = NM - 1 - idx0;
    float dv = Db[idx0];

    for (int k = 0; k < NN + MM - 1; ++k) {
        const int j = k - i;

        // prefetch next element of this row (issued before LDS-dependent math,
        // overlaps with compute + barrier drain)
        const int jn = j + 1;
        const bool pn = (jn >= 0) && (jn < MM);
        float dnext = 0.f;
        if (pn) {
            int idx2 = i * MM + jn;
            if (dir) idx2 = NM - 1 - idx2;
            dnext = Db[idx2];
        }

        float* cur       = buf[k % 3];
        const float* p1  = buf[(k + 2) % 3];  // diagonal k-1
        const float* p2  = buf[(k + 1) % 3];  // diagonal k-2

        if (j >= 0 && j < MM) {
            // virtual boundary: R_pad[0,0]=0, all other boundary = NEG
            float dg = (i == 0) ? ((j == 0) ? 0.f : NEGV)
                                : ((j == 0) ? NEGV : p2[i - 1]);
            float up = (i == 0) ? NEGV : p1[i - 1];
            float lf = (j == 0) ? NEGV : p1[i];
            float m = fmaxf(fmaxf(dg, up), lf);
            // one arg equals m -> log argument in [1,3]: safe for fast math
            float val = dv + m +
                __logf(__expf(dg - m) + __expf(up - m) + __expf(lf - m));
            cur[i] = val;
            int idx = i * MM + j;
            if (dir) idx = NM - 1 - idx;
            R[idx] = val;
        }
        if (pn) dv = dnext;
        __syncthreads();
    }
}

// ---------------------------------------------------------------------------
// block-level max reduction (256 threads)
// ---------------------------------------------------------------------------
__device__ inline float blockMax256(float v) {
    __shared__ float sm[256];
    sm[threadIdx.x] = v;
    __syncthreads();
    for (int s = 128; s > 0; s >>= 1) {
        if ((int)threadIdx.x < s)
            sm[threadIdx.x] = fmaxf(sm[threadIdx.x], sm[threadIdx.x + s]);
        __syncthreads();
    }
    return sm[0];
}

// K2: logit = f + b - d (in place into out, which holds f), per-block max
__global__ __launch_bounds__(256) void logit_kernel(const float* __restrict__ D,
                                                    const float* __restrict__ Rb,
                                                    float* __restrict__ out,
                                                    float* __restrict__ partial) {
    float mx = NEGV;
    const size_t stride = (size_t)gridDim.x * blockDim.x;
    for (size_t idx = (size_t)blockIdx.x * blockDim.x + threadIdx.x; idx < TOTAL;
         idx += stride) {
        float v = out[idx] + Rb[idx] - D[idx];
        out[idx] = v;
        mx = fmaxf(mx, v);
    }
    float bm = blockMax256(mx);
    if (threadIdx.x == 0) partial[blockIdx.x] = bm;
}

// K3: reduce partials to one scalar
__global__ __launch_bounds__(256) void finalmax_kernel(const float* __restrict__ partial,
                                                       int n,
                                                       float* __restrict__ outmax) {
    float mx = NEGV;
    for (int i = threadIdx.x; i < n; i += 256) mx = fmaxf(mx, partial[i]);
    float bm = blockMax256(mx);
    if (threadIdx.x == 0) *outmax = bm;
}

// K4: out -= max  (GAMMA = T = 1)
__global__ __launch_bounds__(256) void sub_kernel(float* __restrict__ out,
                                                  const float* __restrict__ maxp) {
    const float mx = *maxp;
    const size_t stride = (size_t)gridDim.x * blockDim.x;
    for (size_t idx = (size_t)blockIdx.x * blockDim.x + threadIdx.x; idx < TOTAL;
         idx += stride) {
        out[idx] -= mx;
    }
}

extern "C" void kernel_launch(void* const* d_in, const int* in_sizes, int n_in,
                              void* d_out, int out_size, void* d_ws, size_t ws_size,
                              hipStream_t stream) {
    const float* D = (const float*)d_in[0];
    float* out = (float*)d_out;      // holds Rf after K1, logit after K2
    float* Rb = (float*)d_ws;        // 64 MB backward DP result
    float* partial = Rb + TOTAL;     // 2048 floats
    float* maxp = partial + 2048;    // 1 float

    dp_kernel<<<128, 512, 0, stream>>>(D, out, Rb);
    logit_kernel<<<2048, 256, 0, stream>>>(D, Rb, out, partial);
    finalmax_kernel<<<1, 256, 0, stream>>>(partial, 2048, maxp);
    sub_kernel<<<2048, 256, 0, stream>>>(out, maxp);
}